// Round 13
// baseline (1201.868 us; speedup 1.0000x reference)
//
#include <hip/hip_runtime.h>

#define NSEQ 32768
#define NB 8
#define NC 16
#define LBLK 1024          // layer0 grid (NB*NSEQ/256)
#define LPX (LBLK / 8)     // layer0 logical blocks per XCD = 128
#define QGRD 4096          // single-layer grid (NB*NSEQ/64), 4 threads/position
#define QPX (QGRD / 8)     // single-layer logical blocks per XCD = 512
#define GGRD 512           // group grid (NB*NSEQ/512)
#define GPX (GGRD / 8)     // group logical blocks per XCD = 64
#define GBUF 768           // 512-output tile + 256 halo

__device__ __forceinline__ float sigm_f(float x) {
    return __fdividef(1.f, 1.f + __expf(-x));
}
__device__ __forceinline__ float tanh_f(float x) {
    return __fdividef(2.f, 1.f + __expf(-2.f * x)) - 1.f;
}

// Layer 0 (byte-identical to round 12 — FROZEN)
__global__ __launch_bounds__(256) void k_layer0(
    const float* __restrict__ x, const float* __restrict__ w0,
    const float* __restrict__ b0, float* __restrict__ h)
{
    int bid = blockIdx.x;
    int tid = ((bid & 7) * LPX + (bid >> 3)) * 256 + threadIdx.x;
    int n = tid & (NSEQ - 1);
    const float inv = 1.f / 32768.f;
    float xc = x[tid] * inv;
    float xp = (n >= 1) ? x[tid - 1] * inv : 0.f;
    float v[NC];
#pragma unroll
    for (int c = 0; c < NC; c++) {
        float o = w0[c * 2] * xp + w0[c * 2 + 1] * xc + b0[c];
        v[c] = xc + o;
    }
    float4* ph = (float4*)(h + (size_t)tid * NC);
#pragma unroll
    for (int i = 0; i < 4; i++)
        ph[i] = make_float4(v[i * 4], v[i * 4 + 1], v[i * 4 + 2], v[i * 4 + 3]);
}

// Single gated layer, channel-split x4 (byte-identical to round 12 — FROZEN).
// Used for d=256,512 layers (halo too big to fuse).
__global__ __launch_bounds__(256) void k_layer(
    const float* __restrict__ hin, float* __restrict__ hout,
    const float* __restrict__ wf, const float* __restrict__ bf,
    const float* __restrict__ wg, const float* __restrict__ bg, int d)
{
    int bid = blockIdx.x;
    int lbid = (bid & 7) * QPX + (bid >> 3);
    int t = threadIdx.x;
    int pos = lbid * 64 + (t & 63);
    int q = __builtin_amdgcn_readfirstlane(t >> 6);
    int n = pos & (NSEQ - 1);

    float hc[NC], hp[NC];
    {
        const float4* pc = (const float4*)(hin + (size_t)pos * NC);
#pragma unroll
        for (int i = 0; i < 4; i++) {
            float4 tv = pc[i];
            hc[i * 4] = tv.x; hc[i * 4 + 1] = tv.y; hc[i * 4 + 2] = tv.z; hc[i * 4 + 3] = tv.w;
        }
    }
    if (n >= d) {
        const float4* pp = (const float4*)(hin + (size_t)(pos - d) * NC);
#pragma unroll
        for (int i = 0; i < 4; i++) {
            float4 tv = pp[i];
            hp[i * 4] = tv.x; hp[i * 4 + 1] = tv.y; hp[i * 4 + 2] = tv.z; hp[i * 4 + 3] = tv.w;
        }
    } else {
#pragma unroll
        for (int i = 0; i < NC; i++) hp[i] = 0.f;
    }

    const int c0 = q * 4;
    float f[4], g[4];
#pragma unroll
    for (int j = 0; j < 4; j++) { f[j] = bf[c0 + j]; g[j] = bg[c0 + j]; }

#pragma unroll
    for (int ci = 0; ci < NC; ci++) {
        float xp = hp[ci], xc = hc[ci];
#pragma unroll
        for (int j = 0; j < 4; j++) {
            int co = c0 + j;
            f[j] = fmaf(wf[(co * NC + ci) * 2 + 0], xp, f[j]);
            f[j] = fmaf(wf[(co * NC + ci) * 2 + 1], xc, f[j]);
            g[j] = fmaf(wg[(co * NC + ci) * 2 + 0], xp, g[j]);
            g[j] = fmaf(wg[(co * NC + ci) * 2 + 1], xc, g[j]);
        }
    }

    float v[4];
#pragma unroll
    for (int j = 0; j < 4; j++) {
        float outv = tanh_f(f[j]) * sigm_f(g[j]);
        v[j] = hc[c0 + j] + outv;
    }
    float4* po = (float4*)(hout + (size_t)pos * NC + c0);
    po[0] = make_float4(v[0], v[1], v[2], v[3]);
}

// Fused group of nl layers (all dilations in group sum to <= 255).
// Block owns 512 outputs + 256-position left halo in LDS; in-place update
// with read->barrier->write per layer. Per-position math text = frozen r11
// 16-channel chain. Garbage from the window edge propagates < 256 positions,
// never reaching the output region; wb==0 halo stays 0 (= causal zero-pad).
__global__ __launch_bounds__(256, 2) void k_group(
    const float* __restrict__ hin, float* __restrict__ hout,
    const float* __restrict__ wf, const float* __restrict__ bf,
    const float* __restrict__ wg, const float* __restrict__ bg,
    int i0, int nl)
{
    __shared__ float hs[NC][GBUF];     // 48 KiB
    int bid = blockIdx.x;
    int blk = (bid & 7) * GPX + (bid >> 3);   // XCD swizzle: batch b -> XCD b
    int t = threadIdx.x;
    int wb = blk & 63;                 // block index within batch

    // ---- load window [blk*512 - 256, blk*512 + 512) ------------------------
#pragma unroll
    for (int k = 0; k < 3; k++) {
        int idx = t + k * 256;
        if (wb > 0 || idx >= 256) {
            const float4* ph = (const float4*)(hin + ((size_t)blk * 512 + idx - 256) * NC);
#pragma unroll
            for (int i4 = 0; i4 < 4; i4++) {
                float4 tv = ph[i4];
                hs[i4 * 4 + 0][idx] = tv.x; hs[i4 * 4 + 1][idx] = tv.y;
                hs[i4 * 4 + 2][idx] = tv.z; hs[i4 * 4 + 3][idx] = tv.w;
            }
        } else {
#pragma unroll
            for (int c = 0; c < NC; c++) hs[c][idx] = 0.f;
        }
    }
    __syncthreads();

#pragma unroll 1
    for (int j = 0; j < nl; j++) {
        const int i = i0 + j;
        const int d = 1 << (i % 10);
        const float* wfl = wf + (size_t)(i - 1) * NC * NC * 2;
        const float* bfl = bf + (size_t)(i - 1) * NC;
        const float* wgl = wg + (size_t)(i - 1) * NC * NC * 2;
        const float* bgl = bg + (size_t)(i - 1) * NC;

        float v[3][NC];
#pragma unroll
        for (int k = 0; k < 3; k++) {
            const int idx = t + k * 256;
            float hc[NC], hp[NC];
#pragma unroll
            for (int c = 0; c < NC; c++) hc[c] = hs[c][idx];
            if (idx >= d) {
#pragma unroll
                for (int c = 0; c < NC; c++) hp[c] = hs[c][idx - d];
            } else {
#pragma unroll
                for (int c = 0; c < NC; c++) hp[c] = 0.f;
            }

            float f[NC], g[NC];
#pragma unroll
            for (int co = 0; co < NC; co++) { f[co] = bfl[co]; g[co] = bgl[co]; }

#pragma unroll
            for (int ci = 0; ci < NC; ci++) {
                float xp = hp[ci], xc = hc[ci];
#pragma unroll
                for (int co = 0; co < NC; co++) {
                    f[co] = fmaf(wfl[(co * NC + ci) * 2 + 0], xp, f[co]);
                    f[co] = fmaf(wfl[(co * NC + ci) * 2 + 1], xc, f[co]);
                    g[co] = fmaf(wgl[(co * NC + ci) * 2 + 0], xp, g[co]);
                    g[co] = fmaf(wgl[(co * NC + ci) * 2 + 1], xc, g[co]);
                }
            }

#pragma unroll
            for (int co = 0; co < NC; co++) {
                float outv = tanh_f(f[co]) * sigm_f(g[co]);
                v[k][co] = hc[co] + outv;
            }
        }
        __syncthreads();   // all reads of layer input complete
#pragma unroll
        for (int k = 0; k < 3; k++) {
            const int idx = t + k * 256;
            if (wb > 0 || idx >= 256) {
#pragma unroll
                for (int c = 0; c < NC; c++) hs[c][idx] = v[k][c];
            }
        }
        __syncthreads();   // layer output visible
    }

    // ---- store outputs [blk*512, blk*512 + 512) ----------------------------
#pragma unroll
    for (int k = 0; k < 2; k++) {
        int idx = 256 + t + k * 256;
        float4* po = (float4*)(hout + ((size_t)blk * 512 + idx - 256) * NC);
#pragma unroll
        for (int i4 = 0; i4 < 4; i4++)
            po[i4] = make_float4(hs[i4 * 4 + 0][idx], hs[i4 * 4 + 1][idx],
                                 hs[i4 * 4 + 2][idx], hs[i4 * 4 + 3][idx]);
    }
}

// Head v2 (byte-identical to round 12 — FROZEN)
__global__ __launch_bounds__(512, 2) void k_final(
    const float* __restrict__ hfin, const float* __restrict__ x,
    const int* __restrict__ lengths,
    const float* __restrict__ wa, const float* __restrict__ ba,
    const float* __restrict__ wo, const float* __restrict__ bo,
    float* __restrict__ out)
{
    __shared__ float s_r[64][17];
    __shared__ float s_ra[64][65];
    __shared__ float s_red[2][8][64];

    int t = threadIdx.x;
    int p = t & 63;
    int q = __builtin_amdgcn_readfirstlane(t >> 6);
    int blk = blockIdx.x;
    int b = blk >> 9;
    int n0 = (blk & 511) << 6;
    int n = n0 + p;
    size_t pos = (size_t)b * NSEQ + n;
    float xin = x[pos] * (1.f / 32768.f);

    if (q < 4) {
        const float4* ph = (const float4*)(hfin + pos * NC);
        float4 v = ph[q];
        s_r[p][q * 4 + 0] = fmaxf(v.x - xin, 0.f);
        s_r[p][q * 4 + 1] = fmaxf(v.y - xin, 0.f);
        s_r[p][q * 4 + 2] = fmaxf(v.z - xin, 0.f);
        s_r[p][q * 4 + 3] = fmaxf(v.w - xin, 0.f);
    }
    __syncthreads();

    {
        float r[NC];
#pragma unroll
        for (int c = 0; c < NC; c++) r[c] = s_r[p][c];
#pragma unroll
        for (int jj = 0; jj < 8; jj++) {
            int j = q * 8 + jj;
            float acc = ba[j];
#pragma unroll
            for (int c = 0; c < NC; c++) acc = fmaf(wa[j * NC + c], r[c], acc);
            s_ra[p][j] = fmaxf(acc, 0.f);
        }
    }
    __syncthreads();

    float ra[64];
#pragma unroll
    for (int j = 0; j < 64; j++) ra[j] = s_ra[p][j];

    float o[32];
    float m = -1e30f;
#pragma unroll 4
    for (int kk = 0; kk < 32; kk++) {
        int k = q * 32 + kk;
        float acc = bo[k];
#pragma unroll
        for (int j = 0; j < 64; j++) acc = fmaf(wo[k * 64 + j], ra[j], acc);
        o[kk] = acc;
        m = fmaxf(m, acc);
    }
    s_red[0][q][p] = m;
    __syncthreads();
    m = fmaxf(fmaxf(fmaxf(s_red[0][0][p], s_red[0][1][p]),
                    fmaxf(s_red[0][2][p], s_red[0][3][p])),
              fmaxf(fmaxf(s_red[0][4][p], s_red[0][5][p]),
                    fmaxf(s_red[0][6][p], s_red[0][7][p])));
    float s = 0.f;
#pragma unroll
    for (int kk = 0; kk < 32; kk++) s += __expf(o[kk] - m);
    s_red[1][q][p] = s;
    __syncthreads();
    s = ((s_red[1][0][p] + s_red[1][1][p]) + (s_red[1][2][p] + s_red[1][3][p]))
      + ((s_red[1][4][p] + s_red[1][5][p]) + (s_red[1][6][p] + s_red[1][7][p]));
    float lse = m + __logf(s);

    bool valid = n < lengths[b];
    float* po = out + ((size_t)b * 256 + q * 32) * NSEQ + n;
#pragma unroll
    for (int kk = 0; kk < 32; kk++) {
        float v = valid ? (o[kk] - lse) : 0.f;
        __builtin_nontemporal_store(v, &po[(size_t)kk * NSEQ]);
    }
}

extern "C" void kernel_launch(void* const* d_in, const int* in_sizes, int n_in,
                              void* d_out, int out_size, void* d_ws, size_t ws_size,
                              hipStream_t stream) {
    const float* x   = (const float*)d_in[0];
    const int* lens  = (const int*)d_in[1];
    const float* w0  = (const float*)d_in[2];
    const float* b0  = (const float*)d_in[3];
    const float* wf  = (const float*)d_in[4];
    const float* bf  = (const float*)d_in[5];
    const float* wg  = (const float*)d_in[6];
    const float* bg  = (const float*)d_in[7];
    const float* wa  = (const float*)d_in[8];
    const float* ba  = (const float*)d_in[9];
    const float* wo  = (const float*)d_in[10];
    const float* bo  = (const float*)d_in[11];
    float* out = (float*)d_out;

    float* hA = (float*)d_ws;                          // [B][N][16]
    float* hB = hA + (size_t)NB * NSEQ * NC;           // ping-pong (32 MiB total)

    auto WF = [&](int i) { return wf + (size_t)(i - 1) * NC * NC * 2; };
    auto BF = [&](int i) { return bf + (size_t)(i - 1) * NC; };
    auto WG = [&](int i) { return wg + (size_t)(i - 1) * NC * NC * 2; };
    auto BG = [&](int i) { return bg + (size_t)(i - 1) * NC; };

    k_layer0<<<dim3(LBLK), dim3(256), 0, stream>>>(x, w0, b0, hA);

    // layers 1..7 fused (d = 2..128, halo 254)
    k_group<<<dim3(GGRD), dim3(256), 0, stream>>>(hA, hB, wf, bf, wg, bg, 1, 7);
    k_layer<<<dim3(QGRD), dim3(256), 0, stream>>>(hB, hA, WF(8), BF(8), WG(8), BG(8), 256);
    k_layer<<<dim3(QGRD), dim3(256), 0, stream>>>(hA, hB, WF(9), BF(9), WG(9), BG(9), 512);
    // layers 10..17 fused (d = 1..128, halo 255)
    k_group<<<dim3(GGRD), dim3(256), 0, stream>>>(hB, hA, wf, bf, wg, bg, 10, 8);
    k_layer<<<dim3(QGRD), dim3(256), 0, stream>>>(hA, hB, WF(18), BF(18), WG(18), BG(18), 256);
    k_layer<<<dim3(QGRD), dim3(256), 0, stream>>>(hB, hA, WF(19), BF(19), WG(19), BG(19), 512);
    // layers 20..27 fused (d = 1..128, halo 255)
    k_group<<<dim3(GGRD), dim3(256), 0, stream>>>(hA, hB, wf, bf, wg, bg, 20, 8);
    k_layer<<<dim3(QGRD), dim3(256), 0, stream>>>(hB, hA, WF(28), BF(28), WG(28), BG(28), 256);
    k_layer<<<dim3(QGRD), dim3(256), 0, stream>>>(hA, hB, WF(29), BF(29), WG(29), BG(29), 512);

    dim3 fgrd(NB * (NSEQ / 64));
    k_final<<<fgrd, dim3(512), 0, stream>>>(hB, x, lens, wa, ba, wo, bo, out);
}

// Round 15
// 615.659 us; speedup vs baseline: 1.9522x; 1.9522x over previous
//
#include <hip/hip_runtime.h>

#define NSEQ 32768
#define NB 8
#define NC 16
#define LBLK 1024          // layer0 grid (NB*NSEQ/256)
#define LPX (LBLK / 8)     // layer0 logical blocks per XCD = 128
#define QGRD 4096          // gated-layer grid (NB*NSEQ/64), 4 threads/position
#define QPX (QGRD / 8)     // gated-layer logical blocks per XCD = 512

typedef float vfloat4 __attribute__((ext_vector_type(4)));   // native vec for nontemporal builtin

__device__ __forceinline__ float sigm_f(float x) {
    return __fdividef(1.f, 1.f + __expf(-x));
}
__device__ __forceinline__ float tanh_f(float x) {
    return __fdividef(2.f, 1.f + __expf(-2.f * x)) - 1.f;
}

__device__ __forceinline__ void nt_store4(float* p, float a, float b, float c, float d) {
    vfloat4 v; v.x = a; v.y = b; v.z = c; v.w = d;
    __builtin_nontemporal_store(v, (vfloat4*)p);
}

// Layer 0 (math FROZEN; stores nontemporal — value-identical)
__global__ __launch_bounds__(256) void k_layer0(
    const float* __restrict__ x, const float* __restrict__ w0,
    const float* __restrict__ b0, float* __restrict__ h)
{
    int bid = blockIdx.x;
    int tid = ((bid & 7) * LPX + (bid >> 3)) * 256 + threadIdx.x;
    int n = tid & (NSEQ - 1);
    const float inv = 1.f / 32768.f;
    float xc = x[tid] * inv;
    float xp = (n >= 1) ? x[tid - 1] * inv : 0.f;
    float v[NC];
#pragma unroll
    for (int c = 0; c < NC; c++) {
        float o = w0[c * 2] * xp + w0[c * 2 + 1] * xc + b0[c];
        v[c] = xc + o;
    }
    float* ph = h + (size_t)tid * NC;
#pragma unroll
    for (int i = 0; i < 4; i++)
        nt_store4(ph + i * 4, v[i * 4], v[i * 4 + 1], v[i * 4 + 2], v[i * 4 + 3]);
}

// Gated layer, channel-split x4 (math FROZEN, byte-identical chains to r12);
// hout store nontemporal: kills the 16MB/layer RFO fetch on the destination.
__global__ __launch_bounds__(256) void k_layer(
    const float* __restrict__ hin, float* __restrict__ hout,
    const float* __restrict__ wf, const float* __restrict__ bf,
    const float* __restrict__ wg, const float* __restrict__ bg, int d)
{
    int bid = blockIdx.x;
    int lbid = (bid & 7) * QPX + (bid >> 3);          // XCD swizzle: batch b -> XCD b
    int t = threadIdx.x;
    int pos = lbid * 64 + (t & 63);                   // position over B*N
    int q = __builtin_amdgcn_readfirstlane(t >> 6);   // channel quarter 0..3
    int n = pos & (NSEQ - 1);

    float hc[NC], hp[NC];
    {
        const float4* pc = (const float4*)(hin + (size_t)pos * NC);
#pragma unroll
        for (int i = 0; i < 4; i++) {
            float4 tv = pc[i];
            hc[i * 4] = tv.x; hc[i * 4 + 1] = tv.y; hc[i * 4 + 2] = tv.z; hc[i * 4 + 3] = tv.w;
        }
    }
    if (n >= d) {
        const float4* pp = (const float4*)(hin + (size_t)(pos - d) * NC);
#pragma unroll
        for (int i = 0; i < 4; i++) {
            float4 tv = pp[i];
            hp[i * 4] = tv.x; hp[i * 4 + 1] = tv.y; hp[i * 4 + 2] = tv.z; hp[i * 4 + 3] = tv.w;
        }
    } else {
#pragma unroll
        for (int i = 0; i < NC; i++) hp[i] = 0.f;
    }

    const int c0 = q * 4;
    float f[4], g[4];
#pragma unroll
    for (int j = 0; j < 4; j++) { f[j] = bf[c0 + j]; g[j] = bg[c0 + j]; }

#pragma unroll
    for (int ci = 0; ci < NC; ci++) {
        float xp = hp[ci], xc = hc[ci];
#pragma unroll
        for (int j = 0; j < 4; j++) {
            int co = c0 + j;
            // weights wave-uniform -> scalar loads, SGPR operand per v_fma
            f[j] = fmaf(wf[(co * NC + ci) * 2 + 0], xp, f[j]);
            f[j] = fmaf(wf[(co * NC + ci) * 2 + 1], xc, f[j]);
            g[j] = fmaf(wg[(co * NC + ci) * 2 + 0], xp, g[j]);
            g[j] = fmaf(wg[(co * NC + ci) * 2 + 1], xc, g[j]);
        }
    }

    float v[4];
#pragma unroll
    for (int j = 0; j < 4; j++) {
        float outv = tanh_f(f[j]) * sigm_f(g[j]);
        v[j] = hc[c0 + j] + outv;
    }
    nt_store4(hout + (size_t)pos * NC + c0, v[0], v[1], v[2], v[3]);
}

// Head v2 (byte-identical to round 12 — FROZEN)
__global__ __launch_bounds__(512, 2) void k_final(
    const float* __restrict__ hfin, const float* __restrict__ x,
    const int* __restrict__ lengths,
    const float* __restrict__ wa, const float* __restrict__ ba,
    const float* __restrict__ wo, const float* __restrict__ bo,
    float* __restrict__ out)
{
    __shared__ float s_r[64][17];    // relu(agg), odd stride: conflict-free
    __shared__ float s_ra[64][65];   // relu(a)
    __shared__ float s_red[2][8][64];

    int t = threadIdx.x;
    int p = t & 63;
    int q = __builtin_amdgcn_readfirstlane(t >> 6);   // wave index 0..7, scalar
    int blk = blockIdx.x;
    int b = blk >> 9;                 // 512 tiles of 64 per batch
    int n0 = (blk & 511) << 6;
    int n = n0 + p;
    size_t pos = (size_t)b * NSEQ + n;
    float xin = x[pos] * (1.f / 32768.f);

    // phase 1: waves 0-3 stage relu(h - xin) (identical math text)
    if (q < 4) {
        const float4* ph = (const float4*)(hfin + pos * NC);
        float4 v = ph[q];
        s_r[p][q * 4 + 0] = fmaxf(v.x - xin, 0.f);
        s_r[p][q * 4 + 1] = fmaxf(v.y - xin, 0.f);
        s_r[p][q * 4 + 2] = fmaxf(v.z - xin, 0.f);
        s_r[p][q * 4 + 3] = fmaxf(v.w - xin, 0.f);
    }
    __syncthreads();

    // phase 2: a[j] for j = q*8 .. q*8+7 (same per-j fmaf chain)
    {
        float r[NC];
#pragma unroll
        for (int c = 0; c < NC; c++) r[c] = s_r[p][c];
#pragma unroll
        for (int jj = 0; jj < 8; jj++) {
            int j = q * 8 + jj;
            float acc = ba[j];
#pragma unroll
            for (int c = 0; c < NC; c++) acc = fmaf(wa[j * NC + c], r[c], acc);
            s_ra[p][j] = fmaxf(acc, 0.f);
        }
    }
    __syncthreads();

    // phase 3: o[kk] for k = q*32 .. q*32+31, logsumexp across 8 waves
    float ra[64];
#pragma unroll
    for (int j = 0; j < 64; j++) ra[j] = s_ra[p][j];

    float o[32];
    float m = -1e30f;
#pragma unroll 4
    for (int kk = 0; kk < 32; kk++) {
        int k = q * 32 + kk;
        float acc = bo[k];
#pragma unroll
        for (int j = 0; j < 64; j++) acc = fmaf(wo[k * 64 + j], ra[j], acc);
        o[kk] = acc;
        m = fmaxf(m, acc);
    }
    s_red[0][q][p] = m;
    __syncthreads();
    m = fmaxf(fmaxf(fmaxf(s_red[0][0][p], s_red[0][1][p]),
                    fmaxf(s_red[0][2][p], s_red[0][3][p])),
              fmaxf(fmaxf(s_red[0][4][p], s_red[0][5][p]),
                    fmaxf(s_red[0][6][p], s_red[0][7][p])));
    float s = 0.f;
#pragma unroll
    for (int kk = 0; kk < 32; kk++) s += __expf(o[kk] - m);
    s_red[1][q][p] = s;
    __syncthreads();
    s = ((s_red[1][0][p] + s_red[1][1][p]) + (s_red[1][2][p] + s_red[1][3][p]))
      + ((s_red[1][4][p] + s_red[1][5][p]) + (s_red[1][6][p] + s_red[1][7][p]));
    float lse = m + __logf(s);

    bool valid = n < lengths[b];
    float* po = out + ((size_t)b * 256 + q * 32) * NSEQ + n;
#pragma unroll
    for (int kk = 0; kk < 32; kk++) {
        float v = valid ? (o[kk] - lse) : 0.f;
        __builtin_nontemporal_store(v, &po[(size_t)kk * NSEQ]);
    }
}

extern "C" void kernel_launch(void* const* d_in, const int* in_sizes, int n_in,
                              void* d_out, int out_size, void* d_ws, size_t ws_size,
                              hipStream_t stream) {
    const float* x   = (const float*)d_in[0];
    const int* lens  = (const int*)d_in[1];
    const float* w0  = (const float*)d_in[2];
    const float* b0  = (const float*)d_in[3];
    const float* wf  = (const float*)d_in[4];
    const float* bf  = (const float*)d_in[5];
    const float* wg  = (const float*)d_in[6];
    const float* bg  = (const float*)d_in[7];
    const float* wa  = (const float*)d_in[8];
    const float* ba  = (const float*)d_in[9];
    const float* wo  = (const float*)d_in[10];
    const float* bo  = (const float*)d_in[11];
    float* out = (float*)d_out;

    float* hA = (float*)d_ws;                          // [B][N][16]
    float* hB = hA + (size_t)NB * NSEQ * NC;           // ping-pong (32 MiB total)

    k_layer0<<<dim3(LBLK), dim3(256), 0, stream>>>(x, w0, b0, hA);

    float* cur = hA;
    float* nxt = hB;
    for (int i = 1; i <= 29; i++) {
        int d = 1 << (i % 10);
        k_layer<<<dim3(QGRD), dim3(256), 0, stream>>>(cur, nxt,
                                         wf + (size_t)(i - 1) * NC * NC * 2,
                                         bf + (size_t)(i - 1) * NC,
                                         wg + (size_t)(i - 1) * NC * NC * 2,
                                         bg + (size_t)(i - 1) * NC, d);
        float* tmp = cur; cur = nxt; nxt = tmp;
    }

    dim3 fgrd(NB * (NSEQ / 64));
    k_final<<<fgrd, dim3(512), 0, stream>>>(cur, x, lens, wa, ba, wo, bo, out);
}